// Round 8
// baseline (156.474 us; speedup 1.0000x reference)
//
#include <hip/hip_runtime.h>

#define NB     50000
#define NB4    12500
#define BATCH  256
#define NCYC   20000
#define QSCALE  (127.0f / 3.14159265358979f)
#define DQSCALE (3.14159265358979f / 127.0f)
#define OUTSCALE (1.0f / ((float)NCYC * (float)BATCH))

// Fast atan2 with QSCALE folded in: returns atan2(y,x) * (127/pi).
// Hastings deg-9 odd minimax on [0,1], max err ~1e-5 rad (4e-4 int8 code
// flips => ~1e-7 relative error on the final mean).
__device__ __forceinline__ float fast_atan2q(float y, float x) {
    const float ax = __builtin_fabsf(x);
    const float ay = __builtin_fabsf(y);
    const float mx = fmaxf(ax, ay);
    const float mn = fminf(ax, ay);
    const float t  = mn * __builtin_amdgcn_rcpf(mx);   // in [0,1]
    const float t2 = t * t;
    // coefficients pre-scaled by 127/pi
    float p = fmaf(t2, fmaf(t2, fmaf(t2, fmaf(t2,
                  0.84219761f, -3.44137383f), 7.28200966f), -13.35163894f),
                  40.42416382f);
    p *= t;
    p = (ay > ax) ? (63.5f - p) : p;     // 127/pi * (pi/2 - atan)
    p = (x < 0.0f) ? (127.0f - p) : p;   // 127/pi * (pi - atan)
    return copysignf(p, y);
}

__device__ __forceinline__ unsigned int q8(float y, float x) {
    return (unsigned int)(unsigned char)(signed char)__float2int_rn(fast_atan2q(y, x));
}

// ---- kernel 1: transpose + atan2 + int8 quantize -> th[NB][BATCH] --------
// WIDE-READ register transpose. Lane = float4 column: each wave-load is
// 64 lanes x 16 B = 1 KB contiguous (vs 256 B in prior variants -> DRAM
// page efficiency). Wave owns 16 b-rows x 256 nb: 32 wide loads, pack
// int8 per row (lane holds 16 words = 16 b x its 4 nb), then in-lane
// byte transpose (v_perm) -> 4 x uint4 -> 4 x 16 B stores. No LDS.
// Grid (196, 4) = 784 blocks. row_start precompute on blockIdx.y==0.
__global__ __launch_bounds__(256) void theta_k(
        const float4* __restrict__ c4, const float4* __restrict__ s4,
        signed char* __restrict__ th, int* __restrict__ row_start,
        const int* __restrict__ rows, int E) {
    const int u = threadIdx.x;
    if (blockIdx.y == 0) {
        const int g = blockIdx.x * 256 + u;
        if (g <= NCYC) {
            int lo = 0, hi = E;
            while (lo < hi) { const int m = (lo + hi) >> 1; if (rows[m] < g) lo = m + 1; else hi = m; }
            row_start[g] = lo;
        }
    }

    const int lane = u & 63;
    const int w    = u >> 6;                   // wave 0..3
    const int x4   = blockIdx.x * 64 + lane;   // float4 column
    if (x4 >= NB4) return;                     // tail lanes of last block
    const int b0   = blockIdx.y * 64 + 16 * w; // this wave's 16 b-rows

    unsigned int pw[16];                       // pw[r] = 4 nb bytes of row r
    #pragma unroll
    for (int r = 0; r < 16; ++r) {
        const float4 vc = c4[(size_t)(b0 + r) * NB4 + x4];
        const float4 vs = s4[(size_t)(b0 + r) * NB4 + x4];
        pw[r] =  q8(vs.x, vc.x)
              | (q8(vs.y, vc.y) << 8)
              | (q8(vs.z, vc.z) << 16)
              | (q8(vs.w, vc.w) << 24);
    }

    // in-lane 4x16 byte transpose: out word q of nb j = byte j of rows 4q..4q+3
    #pragma unroll
    for (int j = 0; j < 4; ++j) {
        uint4 o;
        unsigned int* op = &o.x;
        #pragma unroll
        for (int q = 0; q < 4; ++q) {
            const unsigned int sh = 8 * j;
            op[q] =  ((pw[4 * q + 0] >> sh) & 0xffu)
                  | (((pw[4 * q + 1] >> sh) & 0xffu) << 8)
                  | (((pw[4 * q + 2] >> sh) & 0xffu) << 16)
                  | (((pw[4 * q + 3] >> sh) & 0xffu) << 24);
        }
        const int nb = 4 * x4 + j;             // < NB by construction
        *reinterpret_cast<uint4*>(&th[(size_t)nb * BATCH + b0]) = o;
    }
}

// ---- kernel 2: wave per row (4/block), precomputed bounds, NO fences,
//      one partial per block ----------------------------------------------
__global__ __launch_bounds__(256) void kvl3_k(
        const signed char* __restrict__ th,
        const float* __restrict__ signs, const int* __restrict__ inds,
        const int* __restrict__ row_start,
        float* __restrict__ partials) {
    __shared__ float wsum[4];
    const int tid  = threadIdx.x;
    const int wave = tid >> 6;
    const int lane = tid & 63;
    const int r    = blockIdx.x * 4 + wave;           // < NCYC (5000*4)
    const int start = row_start[r];
    const int end   = row_start[r + 1];

    float a0 = 0.f, a1 = 0.f, a2 = 0.f, a3 = 0.f;
    int e = start;
    for (; e + 2 <= end; e += 2) {
        const int   i0 = inds[e],  i1 = inds[e + 1];
        const float g0 = signs[e] * DQSCALE, g1 = signs[e + 1] * DQSCALE;
        const unsigned int u0 = *reinterpret_cast<const unsigned int*>(&th[(size_t)i0 * BATCH + lane * 4]);
        const unsigned int u1 = *reinterpret_cast<const unsigned int*>(&th[(size_t)i1 * BATCH + lane * 4]);
        a0 += g0 * (float)(signed char)(u0      ) + g1 * (float)(signed char)(u1      );
        a1 += g0 * (float)(signed char)(u0 >>  8) + g1 * (float)(signed char)(u1 >>  8);
        a2 += g0 * (float)(signed char)(u0 >> 16) + g1 * (float)(signed char)(u1 >> 16);
        a3 += g0 * (float)(signed char)(u0 >> 24) + g1 * (float)(signed char)(u1 >> 24);
    }
    if (e < end) {
        const float g0 = signs[e] * DQSCALE;
        const unsigned int u0 = *reinterpret_cast<const unsigned int*>(&th[(size_t)inds[e] * BATCH + lane * 4]);
        a0 += g0 * (float)(signed char)(u0      );
        a1 += g0 * (float)(signed char)(u0 >>  8);
        a2 += g0 * (float)(signed char)(u0 >> 16);
        a3 += g0 * (float)(signed char)(u0 >> 24);
    }
    float v = fabsf(a0) + fabsf(a1) + fabsf(a2) + fabsf(a3);
    #pragma unroll
    for (int off = 32; off > 0; off >>= 1)
        v += __shfl_down(v, off, 64);
    if (lane == 0) wsum[wave] = v;
    __syncthreads();
    if (tid == 0)
        partials[blockIdx.x] = wsum[0] + wsum[1] + wsum[2] + wsum[3];
}

// ---- kernel 3: single block reduces 5000 block partials -> out[0] ---------
__global__ __launch_bounds__(1024) void reduce_k(
        const float* __restrict__ partials, float* __restrict__ out) {
    const int tid = threadIdx.x;
    float v = 0.f;
    for (int i = tid; i < NCYC / 4; i += 1024) v += partials[i];
    #pragma unroll
    for (int off = 32; off > 0; off >>= 1)
        v += __shfl_down(v, off, 64);
    __shared__ float wsum[16];
    if ((tid & 63) == 0) wsum[tid >> 6] = v;
    __syncthreads();
    if (tid == 0) {
        float t = 0.f;
        #pragma unroll
        for (int w = 0; w < 16; ++w) t += wsum[w];
        out[0] = t * OUTSCALE;
    }
}

// ---- fallback (no workspace): direct strided gather -----------------------
__global__ void zero_out_k(float* out) { if (threadIdx.x == 0) out[0] = 0.0f; }

__global__ __launch_bounds__(256) void kvl_fallback_k(
        const float* __restrict__ c, const float* __restrict__ s,
        const float* __restrict__ signs, const int* __restrict__ inds,
        const int* __restrict__ rows, int E, float* __restrict__ out) {
    const int r = blockIdx.x;
    int lo = 0, hi = E;
    while (lo < hi) { const int m = (lo + hi) >> 1; if (rows[m] < r) lo = m + 1; else hi = m; }
    const int start = lo;
    hi = E;
    while (lo < hi) { const int m = (lo + hi) >> 1; if (rows[m] <= r) lo = m + 1; else hi = m; }
    const int end = lo;
    const int tid = threadIdx.x;
    float acc = 0.f;
    for (int e = start; e < end; ++e) {
        const int idx = inds[e];
        const float sg = signs[e];
        acc += atan2f(sg * s[(size_t)tid * NB + idx], c[(size_t)tid * NB + idx]);
    }
    float v = fabsf(acc);
    #pragma unroll
    for (int off = 32; off > 0; off >>= 1)
        v += __shfl_down(v, off, 64);
    __shared__ float wsum[4];
    if ((tid & 63) == 0) wsum[tid >> 6] = v;
    __syncthreads();
    if (tid == 0)
        atomicAdd(out, (wsum[0] + wsum[1] + wsum[2] + wsum[3]) *
                       (1.0f / ((float)NCYC * (float)BATCH)));
}

extern "C" void kernel_launch(void* const* d_in, const int* in_sizes, int n_in,
                              void* d_out, int out_size, void* d_ws, size_t ws_size,
                              hipStream_t stream) {
    const float* c       = (const float*)d_in[0];
    const float* s       = (const float*)d_in[1];
    const float* cysigns = (const float*)d_in[2];
    const int*   cyinds  = (const int*)d_in[3];
    const int*   cyrows  = (const int*)d_in[4];
    const int    E       = in_sizes[2];   // 160000
    float* out = (float*)d_out;

    const size_t th_bytes = (size_t)NB * BATCH;            // 12.8 MB int8
    const size_t rs_bytes = (size_t)(NCYC + 1) * sizeof(int);
    const size_t pa_bytes = (size_t)(NCYC / 4) * sizeof(float);
    const size_t need = th_bytes + rs_bytes + pa_bytes;
    if (ws_size >= need) {
        signed char* th   = (signed char*)d_ws;
        int* row_start    = (int*)(th + th_bytes);
        float* partials   = (float*)((char*)row_start + rs_bytes);

        dim3 tg((NB4 + 63) / 64, BATCH / 64);              // (196, 4)
        theta_k<<<tg, 256, 0, stream>>>((const float4*)c, (const float4*)s,
                                        th, row_start, cyrows, E);
        kvl3_k<<<NCYC / 4, 256, 0, stream>>>(th, cysigns, cyinds, row_start,
                                             partials);
        reduce_k<<<1, 1024, 0, stream>>>(partials, out);
    } else {
        zero_out_k<<<1, 64, 0, stream>>>(out);
        kvl_fallback_k<<<NCYC, 256, 0, stream>>>(c, s, cysigns, cyinds, cyrows, E, out);
    }
}

// Round 9
// 152.689 us; speedup vs baseline: 1.0248x; 1.0248x over previous
//
#include <hip/hip_runtime.h>

#define NB     50000
#define NB4    12500
#define BATCH  256
#define NCYC   20000
#define QSCALE  (127.0f / 3.14159265358979f)
#define DQSCALE (3.14159265358979f / 127.0f)
#define OUTSCALE (1.0f / ((float)NCYC * (float)BATCH))

// Fast atan2 with QSCALE folded in: returns atan2(y,x) * (127/pi).
// Hastings deg-9 odd minimax on [0,1], max err ~1e-5 rad (4e-4 int8 code
// flips => ~1e-7 relative error on the final mean).
__device__ __forceinline__ float fast_atan2q(float y, float x) {
    const float ax = __builtin_fabsf(x);
    const float ay = __builtin_fabsf(y);
    const float mx = fmaxf(ax, ay);
    const float mn = fminf(ax, ay);
    const float t  = mn * __builtin_amdgcn_rcpf(mx);   // in [0,1]
    const float t2 = t * t;
    // coefficients pre-scaled by 127/pi
    float p = fmaf(t2, fmaf(t2, fmaf(t2, fmaf(t2,
                  0.84219761f, -3.44137383f), 7.28200966f), -13.35163894f),
                  40.42416382f);
    p *= t;
    p = (ay > ax) ? (63.5f - p) : p;     // 127/pi * (pi/2 - atan)
    p = (x < 0.0f) ? (127.0f - p) : p;   // 127/pi * (pi - atan)
    return copysignf(p, y);
}

__device__ __forceinline__ unsigned int q8(float y, float x) {
    return (unsigned int)(unsigned char)(signed char)__float2int_rn(fast_atan2q(y, x));
}

// async 16B global -> LDS (no VGPR round-trip, deep in-flight queue)
__device__ __forceinline__ void gload16(const void* g, void* l) {
    __builtin_amdgcn_global_load_lds(
        (const __attribute__((address_space(1))) void*)g,
        (__attribute__((address_space(3))) void*)l,
        16, 0, 0);
}

// ---- kernel 1: transpose + atan2 + int8 quantize -> th[NB][BATCH] --------
// global_load_lds staging: block tile = 16 b-rows x 256 nb. Each staging
// instruction moves 1 KB contiguous (64 lanes x 16 B) async into LDS with
// zero VGPR cost -> high MLP at 5 blocks/CU (32 KB LDS), ~20 waves/CU.
// Compute: thread u owns nb column bx*256+u: 32 conflict-free ds_read_b32
// (lane-consecutive), 16 atan2, pack 4 words, one 16 B store.
// Grid (196, 16) = 3136 blocks. row_start precompute on blockIdx.y==0.
__global__ __launch_bounds__(256) void theta_k(
        const float4* __restrict__ c4, const float4* __restrict__ s4,
        signed char* __restrict__ th, int* __restrict__ row_start,
        const int* __restrict__ rows, int E) {
    __shared__ float4 ct[16][64];           // 16 KB
    __shared__ float4 st[16][64];           // 16 KB
    const int u = threadIdx.x;

    if (blockIdx.y == 0) {
        const int g = blockIdx.x * 256 + u;
        if (g <= NCYC) {
            int lo = 0, hi = E;
            while (lo < hi) { const int m = (lo + hi) >> 1; if (rows[m] < g) lo = m + 1; else hi = m; }
            row_start[g] = lo;
        }
    }

    const int lane  = u & 63;
    const int w     = u >> 6;               // wave 0..3
    const int brow0 = blockIdx.y * 16;
    int col = blockIdx.x * 64 + lane;       // float4 column
    if (col > NB4 - 1) col = NB4 - 1;       // clamp (garbage ok, store-guarded)

    // stage: wave w loads rows 4w..4w+3 of c and s (1 KB per instruction)
    #pragma unroll
    for (int i = 0; i < 4; ++i) {
        const int r = 4 * w + i;
        gload16(&c4[(size_t)(brow0 + r) * NB4 + col], &ct[r][0]);
        gload16(&s4[(size_t)(brow0 + r) * NB4 + col], &st[r][0]);
    }
    __syncthreads();                        // drains vmcnt, all tiles visible

    // compute: thread u = nb column (bx*256+u); reads are lane-consecutive
    const float* cf = reinterpret_cast<const float*>(ct);
    const float* sf = reinterpret_cast<const float*>(st);
    unsigned int wv[4] = {0u, 0u, 0u, 0u};
    #pragma unroll
    for (int r = 0; r < 16; ++r) {
        const float cc = cf[r * 256 + u];
        const float ss = sf[r * 256 + u];
        wv[r >> 2] |= q8(ss, cc) << (8 * (r & 3));
    }

    const int nbg = blockIdx.x * 256 + u;
    if (nbg < NB) {
        uint4 o;
        o.x = wv[0]; o.y = wv[1]; o.z = wv[2]; o.w = wv[3];
        *reinterpret_cast<uint4*>(&th[(size_t)nbg * BATCH + brow0]) = o;
    }
}

// ---- kernel 2: wave per row (4/block), precomputed bounds, NO fences,
//      one partial per block ----------------------------------------------
__global__ __launch_bounds__(256) void kvl3_k(
        const signed char* __restrict__ th,
        const float* __restrict__ signs, const int* __restrict__ inds,
        const int* __restrict__ row_start,
        float* __restrict__ partials) {
    __shared__ float wsum[4];
    const int tid  = threadIdx.x;
    const int wave = tid >> 6;
    const int lane = tid & 63;
    const int r    = blockIdx.x * 4 + wave;           // < NCYC (5000*4)
    const int start = row_start[r];
    const int end   = row_start[r + 1];

    float a0 = 0.f, a1 = 0.f, a2 = 0.f, a3 = 0.f;
    int e = start;
    for (; e + 2 <= end; e += 2) {
        const int   i0 = inds[e],  i1 = inds[e + 1];
        const float g0 = signs[e] * DQSCALE, g1 = signs[e + 1] * DQSCALE;
        const unsigned int u0 = *reinterpret_cast<const unsigned int*>(&th[(size_t)i0 * BATCH + lane * 4]);
        const unsigned int u1 = *reinterpret_cast<const unsigned int*>(&th[(size_t)i1 * BATCH + lane * 4]);
        a0 += g0 * (float)(signed char)(u0      ) + g1 * (float)(signed char)(u1      );
        a1 += g0 * (float)(signed char)(u0 >>  8) + g1 * (float)(signed char)(u1 >>  8);
        a2 += g0 * (float)(signed char)(u0 >> 16) + g1 * (float)(signed char)(u1 >> 16);
        a3 += g0 * (float)(signed char)(u0 >> 24) + g1 * (float)(signed char)(u1 >> 24);
    }
    if (e < end) {
        const float g0 = signs[e] * DQSCALE;
        const unsigned int u0 = *reinterpret_cast<const unsigned int*>(&th[(size_t)inds[e] * BATCH + lane * 4]);
        a0 += g0 * (float)(signed char)(u0      );
        a1 += g0 * (float)(signed char)(u0 >>  8);
        a2 += g0 * (float)(signed char)(u0 >> 16);
        a3 += g0 * (float)(signed char)(u0 >> 24);
    }
    float v = fabsf(a0) + fabsf(a1) + fabsf(a2) + fabsf(a3);
    #pragma unroll
    for (int off = 32; off > 0; off >>= 1)
        v += __shfl_down(v, off, 64);
    if (lane == 0) wsum[wave] = v;
    __syncthreads();
    if (tid == 0)
        partials[blockIdx.x] = wsum[0] + wsum[1] + wsum[2] + wsum[3];
}

// ---- kernel 3: single block reduces 5000 block partials -> out[0] ---------
__global__ __launch_bounds__(1024) void reduce_k(
        const float* __restrict__ partials, float* __restrict__ out) {
    const int tid = threadIdx.x;
    float v = 0.f;
    for (int i = tid; i < NCYC / 4; i += 1024) v += partials[i];
    #pragma unroll
    for (int off = 32; off > 0; off >>= 1)
        v += __shfl_down(v, off, 64);
    __shared__ float wsum[16];
    if ((tid & 63) == 0) wsum[tid >> 6] = v;
    __syncthreads();
    if (tid == 0) {
        float t = 0.f;
        #pragma unroll
        for (int w = 0; w < 16; ++w) t += wsum[w];
        out[0] = t * OUTSCALE;
    }
}

// ---- fallback (no workspace): direct strided gather -----------------------
__global__ void zero_out_k(float* out) { if (threadIdx.x == 0) out[0] = 0.0f; }

__global__ __launch_bounds__(256) void kvl_fallback_k(
        const float* __restrict__ c, const float* __restrict__ s,
        const float* __restrict__ signs, const int* __restrict__ inds,
        const int* __restrict__ rows, int E, float* __restrict__ out) {
    const int r = blockIdx.x;
    int lo = 0, hi = E;
    while (lo < hi) { const int m = (lo + hi) >> 1; if (rows[m] < r) lo = m + 1; else hi = m; }
    const int start = lo;
    hi = E;
    while (lo < hi) { const int m = (lo + hi) >> 1; if (rows[m] <= r) lo = m + 1; else hi = m; }
    const int end = lo;
    const int tid = threadIdx.x;
    float acc = 0.f;
    for (int e = start; e < end; ++e) {
        const int idx = inds[e];
        const float sg = signs[e];
        acc += atan2f(sg * s[(size_t)tid * NB + idx], c[(size_t)tid * NB + idx]);
    }
    float v = fabsf(acc);
    #pragma unroll
    for (int off = 32; off > 0; off >>= 1)
        v += __shfl_down(v, off, 64);
    __shared__ float wsum[4];
    if ((tid & 63) == 0) wsum[tid >> 6] = v;
    __syncthreads();
    if (tid == 0)
        atomicAdd(out, (wsum[0] + wsum[1] + wsum[2] + wsum[3]) *
                       (1.0f / ((float)NCYC * (float)BATCH)));
}

extern "C" void kernel_launch(void* const* d_in, const int* in_sizes, int n_in,
                              void* d_out, int out_size, void* d_ws, size_t ws_size,
                              hipStream_t stream) {
    const float* c       = (const float*)d_in[0];
    const float* s       = (const float*)d_in[1];
    const float* cysigns = (const float*)d_in[2];
    const int*   cyinds  = (const int*)d_in[3];
    const int*   cyrows  = (const int*)d_in[4];
    const int    E       = in_sizes[2];   // 160000
    float* out = (float*)d_out;

    const size_t th_bytes = (size_t)NB * BATCH;            // 12.8 MB int8
    const size_t rs_bytes = (size_t)(NCYC + 1) * sizeof(int);
    const size_t pa_bytes = (size_t)(NCYC / 4) * sizeof(float);
    const size_t need = th_bytes + rs_bytes + pa_bytes;
    if (ws_size >= need) {
        signed char* th   = (signed char*)d_ws;
        int* row_start    = (int*)(th + th_bytes);
        float* partials   = (float*)((char*)row_start + rs_bytes);

        dim3 tg((NB4 + 63) / 64, 16);                      // (196, 16)
        theta_k<<<tg, 256, 0, stream>>>((const float4*)c, (const float4*)s,
                                        th, row_start, cyrows, E);
        kvl3_k<<<NCYC / 4, 256, 0, stream>>>(th, cysigns, cyinds, row_start,
                                             partials);
        reduce_k<<<1, 1024, 0, stream>>>(partials, out);
    } else {
        zero_out_k<<<1, 64, 0, stream>>>(out);
        kvl_fallback_k<<<NCYC, 256, 0, stream>>>(c, s, cysigns, cyinds, cyrows, E, out);
    }
}

// Round 10
// 150.462 us; speedup vs baseline: 1.0400x; 1.0148x over previous
//
#include <hip/hip_runtime.h>

#define NB     50000
#define NB4    12500
#define BATCH  256
#define NCYC   20000
#define QSCALE  (127.0f / 3.14159265358979f)
#define DQSCALE (3.14159265358979f / 127.0f)
#define OUTSCALE (1.0f / ((float)NCYC * (float)BATCH))

#define WAITV(n) asm volatile("s_waitcnt vmcnt(" #n ")" ::: "memory")

// Fast atan2 with QSCALE folded in: returns atan2(y,x) * (127/pi).
// Hastings deg-9 odd minimax on [0,1], max err ~1e-5 rad (4e-4 int8 code
// flips => ~1e-7 relative error on the final mean).
__device__ __forceinline__ float fast_atan2q(float y, float x) {
    const float ax = __builtin_fabsf(x);
    const float ay = __builtin_fabsf(y);
    const float mx = fmaxf(ax, ay);
    const float mn = fminf(ax, ay);
    const float t  = mn * __builtin_amdgcn_rcpf(mx);   // in [0,1]
    const float t2 = t * t;
    float p = fmaf(t2, fmaf(t2, fmaf(t2, fmaf(t2,
                  0.84219761f, -3.44137383f), 7.28200966f), -13.35163894f),
                  40.42416382f);
    p *= t;
    p = (ay > ax) ? (63.5f - p) : p;     // 127/pi * (pi/2 - atan)
    p = (x < 0.0f) ? (127.0f - p) : p;   // 127/pi * (pi - atan)
    return copysignf(p, y);
}

__device__ __forceinline__ unsigned int q8(float y, float x) {
    return (unsigned int)(unsigned char)(signed char)__float2int_rn(fast_atan2q(y, x));
}

// async 16B global -> LDS (no VGPR round-trip, deep in-flight queue)
__device__ __forceinline__ void gload16(const void* g, void* l) {
    __builtin_amdgcn_global_load_lds(
        (const __attribute__((address_space(1))) void*)g,
        (__attribute__((address_space(3))) void*)l,
        16, 0, 0);
}

template<int T>
__device__ __forceinline__ void compute_tile(
        const float (*cbw)[2][256], const float (*sbw)[2][256],
        int lane, unsigned int acc[4][4]) {
    constexpr int bf = T & 1;
    #pragma unroll
    for (int k = 0; k < 4; ++k) {
        const float c0 = cbw[bf][0][lane + 64 * k];
        const float s0 = sbw[bf][0][lane + 64 * k];
        const float c1 = cbw[bf][1][lane + 64 * k];
        const float s1 = sbw[bf][1][lane + 64 * k];
        acc[k][T >> 1] |= (q8(s0, c0) << (8 * ((2 * T) & 3)))
                        | (q8(s1, c1) << (8 * ((2 * T) & 3) + 8));
    }
}

// ---- kernel 1: transpose + atan2 + int8 quantize -> th[NB][BATCH] --------
// Wave-private double-buffered DMA pipeline. Each wave owns one unit of
// 16 b-rows x 256 nb, processed as 8 tiles of 2 rows. Per tile: 4 x
// global_load_lds (1 KB contiguous each, zero VGPR). NO barriers anywhere
// (waves share nothing) -> no compiler-forced vmcnt(0); explicit counted
// s_waitcnt vmcnt(4) keeps the next tile in flight during compute (T4).
// Output: 16 regs accumulate 16 rows, then 4 x 16 B stores.
// Grid 784 x 256; LDS 32 KB/block -> all blocks resident (~12 waves/CU).
__global__ __launch_bounds__(256) void theta_k(
        const float4* __restrict__ c4, const float4* __restrict__ s4,
        signed char* __restrict__ th, int* __restrict__ row_start,
        const int* __restrict__ rows, int E) {
    __shared__ float cb[4][2][2][256];      // [wave][buf][row][nb_local] 16 KB
    __shared__ float sb[4][2][2][256];      // 16 KB
    const int u = threadIdx.x;

    // row_start[0..NCYC]: one binary search per thread (rows L2-resident)
    {
        const int g = blockIdx.x * 256 + u;
        if (g <= NCYC) {
            int lo = 0, hi = E;
            while (lo < hi) { const int m = (lo + hi) >> 1; if (rows[m] < g) lo = m + 1; else hi = m; }
            row_start[g] = lo;
        }
    }

    const int lane   = u & 63;
    const int w      = u >> 6;
    const int unit   = blockIdx.x * 4 + w;  // 0..3135 = 196 panels x 16 chunks
    const int panel  = unit >> 4;           // 0..195  (256-nb panel)
    const int bchunk = unit & 15;
    const int b0     = bchunk * 16;         // 16 b-rows
    const int nb0    = panel * 256;
    int gcol = panel * 64 + lane;           // float4 column
    if (gcol > NB4 - 1) gcol = NB4 - 1;     // clamp (dup loads, store-guarded)

    #define ISSUE(t) do {                                                    \
        const int rb_ = b0 + 2 * (t);                                        \
        gload16(&c4[(size_t)(rb_    ) * NB4 + gcol], &cb[w][(t) & 1][0][0]); \
        gload16(&c4[(size_t)(rb_ + 1) * NB4 + gcol], &cb[w][(t) & 1][1][0]); \
        gload16(&s4[(size_t)(rb_    ) * NB4 + gcol], &sb[w][(t) & 1][0][0]); \
        gload16(&s4[(size_t)(rb_ + 1) * NB4 + gcol], &sb[w][(t) & 1][1][0]); \
    } while (0)

    unsigned int acc[4][4] = {{0u,0u,0u,0u},{0u,0u,0u,0u},{0u,0u,0u,0u},{0u,0u,0u,0u}};

    ISSUE(0); ISSUE(1);
    WAITV(4); compute_tile<0>(cb[w], sb[w], lane, acc); ISSUE(2);
    WAITV(4); compute_tile<1>(cb[w], sb[w], lane, acc); ISSUE(3);
    WAITV(4); compute_tile<2>(cb[w], sb[w], lane, acc); ISSUE(4);
    WAITV(4); compute_tile<3>(cb[w], sb[w], lane, acc); ISSUE(5);
    WAITV(4); compute_tile<4>(cb[w], sb[w], lane, acc); ISSUE(6);
    WAITV(4); compute_tile<5>(cb[w], sb[w], lane, acc); ISSUE(7);
    WAITV(4); compute_tile<6>(cb[w], sb[w], lane, acc);
    WAITV(0); compute_tile<7>(cb[w], sb[w], lane, acc);
    #undef ISSUE

    #pragma unroll
    for (int k = 0; k < 4; ++k) {
        const int nb = nb0 + lane + 64 * k;
        if (nb < NB) {
            uint4 o;
            o.x = acc[k][0]; o.y = acc[k][1]; o.z = acc[k][2]; o.w = acc[k][3];
            *reinterpret_cast<uint4*>(&th[(size_t)nb * BATCH + b0]) = o;
        }
    }
}

// ---- kernel 2: wave per row (4/block), precomputed bounds, NO fences,
//      4-deep batched gather (rows avg 8 entries), one partial per block --
__global__ __launch_bounds__(256) void kvl3_k(
        const signed char* __restrict__ th,
        const float* __restrict__ signs, const int* __restrict__ inds,
        const int* __restrict__ row_start,
        float* __restrict__ partials) {
    __shared__ float wsum[4];
    const int tid  = threadIdx.x;
    const int wave = tid >> 6;
    const int lane = tid & 63;
    const int r    = blockIdx.x * 4 + wave;           // < NCYC (5000*4)
    const int start = row_start[r];
    const int end   = row_start[r + 1];

    float a0 = 0.f, a1 = 0.f, a2 = 0.f, a3 = 0.f;
    int e = start;
    for (; e + 4 <= end; e += 4) {
        const int   i0 = inds[e],     i1 = inds[e + 1];
        const int   i2 = inds[e + 2], i3 = inds[e + 3];
        const float g0 = signs[e]     * DQSCALE, g1 = signs[e + 1] * DQSCALE;
        const float g2 = signs[e + 2] * DQSCALE, g3 = signs[e + 3] * DQSCALE;
        const unsigned int u0 = *reinterpret_cast<const unsigned int*>(&th[(size_t)i0 * BATCH + lane * 4]);
        const unsigned int u1 = *reinterpret_cast<const unsigned int*>(&th[(size_t)i1 * BATCH + lane * 4]);
        const unsigned int u2 = *reinterpret_cast<const unsigned int*>(&th[(size_t)i2 * BATCH + lane * 4]);
        const unsigned int u3 = *reinterpret_cast<const unsigned int*>(&th[(size_t)i3 * BATCH + lane * 4]);
        a0 += g0 * (float)(signed char)(u0      ) + g1 * (float)(signed char)(u1      )
            + g2 * (float)(signed char)(u2      ) + g3 * (float)(signed char)(u3      );
        a1 += g0 * (float)(signed char)(u0 >>  8) + g1 * (float)(signed char)(u1 >>  8)
            + g2 * (float)(signed char)(u2 >>  8) + g3 * (float)(signed char)(u3 >>  8);
        a2 += g0 * (float)(signed char)(u0 >> 16) + g1 * (float)(signed char)(u1 >> 16)
            + g2 * (float)(signed char)(u2 >> 16) + g3 * (float)(signed char)(u3 >> 16);
        a3 += g0 * (float)(signed char)(u0 >> 24) + g1 * (float)(signed char)(u1 >> 24)
            + g2 * (float)(signed char)(u2 >> 24) + g3 * (float)(signed char)(u3 >> 24);
    }
    for (; e < end; ++e) {
        const float g0 = signs[e] * DQSCALE;
        const unsigned int u0 = *reinterpret_cast<const unsigned int*>(&th[(size_t)inds[e] * BATCH + lane * 4]);
        a0 += g0 * (float)(signed char)(u0      );
        a1 += g0 * (float)(signed char)(u0 >>  8);
        a2 += g0 * (float)(signed char)(u0 >> 16);
        a3 += g0 * (float)(signed char)(u0 >> 24);
    }
    float v = fabsf(a0) + fabsf(a1) + fabsf(a2) + fabsf(a3);
    #pragma unroll
    for (int off = 32; off > 0; off >>= 1)
        v += __shfl_down(v, off, 64);
    if (lane == 0) wsum[wave] = v;
    __syncthreads();
    if (tid == 0)
        partials[blockIdx.x] = wsum[0] + wsum[1] + wsum[2] + wsum[3];
}

// ---- kernel 3: single block reduces 5000 block partials -> out[0] ---------
__global__ __launch_bounds__(1024) void reduce_k(
        const float* __restrict__ partials, float* __restrict__ out) {
    const int tid = threadIdx.x;
    float v = 0.f;
    for (int i = tid; i < NCYC / 4; i += 1024) v += partials[i];
    #pragma unroll
    for (int off = 32; off > 0; off >>= 1)
        v += __shfl_down(v, off, 64);
    __shared__ float wsum[16];
    if ((tid & 63) == 0) wsum[tid >> 6] = v;
    __syncthreads();
    if (tid == 0) {
        float t = 0.f;
        #pragma unroll
        for (int w = 0; w < 16; ++w) t += wsum[w];
        out[0] = t * OUTSCALE;
    }
}

// ---- fallback (no workspace): direct strided gather -----------------------
__global__ void zero_out_k(float* out) { if (threadIdx.x == 0) out[0] = 0.0f; }

__global__ __launch_bounds__(256) void kvl_fallback_k(
        const float* __restrict__ c, const float* __restrict__ s,
        const float* __restrict__ signs, const int* __restrict__ inds,
        const int* __restrict__ rows, int E, float* __restrict__ out) {
    const int r = blockIdx.x;
    int lo = 0, hi = E;
    while (lo < hi) { const int m = (lo + hi) >> 1; if (rows[m] < r) lo = m + 1; else hi = m; }
    const int start = lo;
    hi = E;
    while (lo < hi) { const int m = (lo + hi) >> 1; if (rows[m] <= r) lo = m + 1; else hi = m; }
    const int end = lo;
    const int tid = threadIdx.x;
    float acc = 0.f;
    for (int e = start; e < end; ++e) {
        const int idx = inds[e];
        const float sg = signs[e];
        acc += atan2f(sg * s[(size_t)tid * NB + idx], c[(size_t)tid * NB + idx]);
    }
    float v = fabsf(acc);
    #pragma unroll
    for (int off = 32; off > 0; off >>= 1)
        v += __shfl_down(v, off, 64);
    __shared__ float wsum[4];
    if ((tid & 63) == 0) wsum[tid >> 6] = v;
    __syncthreads();
    if (tid == 0)
        atomicAdd(out, (wsum[0] + wsum[1] + wsum[2] + wsum[3]) *
                       (1.0f / ((float)NCYC * (float)BATCH)));
}

extern "C" void kernel_launch(void* const* d_in, const int* in_sizes, int n_in,
                              void* d_out, int out_size, void* d_ws, size_t ws_size,
                              hipStream_t stream) {
    const float* c       = (const float*)d_in[0];
    const float* s       = (const float*)d_in[1];
    const float* cysigns = (const float*)d_in[2];
    const int*   cyinds  = (const int*)d_in[3];
    const int*   cyrows  = (const int*)d_in[4];
    const int    E       = in_sizes[2];   // 160000
    float* out = (float*)d_out;

    const size_t th_bytes = (size_t)NB * BATCH;            // 12.8 MB int8
    const size_t rs_bytes = (size_t)(NCYC + 1) * sizeof(int);
    const size_t pa_bytes = (size_t)(NCYC / 4) * sizeof(float);
    const size_t need = th_bytes + rs_bytes + pa_bytes;
    if (ws_size >= need) {
        signed char* th   = (signed char*)d_ws;
        int* row_start    = (int*)(th + th_bytes);
        float* partials   = (float*)((char*)row_start + rs_bytes);

        theta_k<<<784, 256, 0, stream>>>((const float4*)c, (const float4*)s,
                                         th, row_start, cyrows, E);
        kvl3_k<<<NCYC / 4, 256, 0, stream>>>(th, cysigns, cyinds, row_start,
                                             partials);
        reduce_k<<<1, 1024, 0, stream>>>(partials, out);
    } else {
        zero_out_k<<<1, 64, 0, stream>>>(out);
        kvl_fallback_k<<<NCYC, 256, 0, stream>>>(c, s, cysigns, cyinds, cyrows, E, out);
    }
}

// Round 11
// 148.342 us; speedup vs baseline: 1.0548x; 1.0143x over previous
//
#include <hip/hip_runtime.h>

#define NB     50000
#define NB4    12500
#define BATCH  256
#define NCYC   20000
#define QSCALE  (127.0f / 3.14159265358979f)
#define DQSCALE (3.14159265358979f / 127.0f)
#define OUTSCALE (1.0f / ((float)NCYC * (float)BATCH))

// Fast atan2 with QSCALE folded in: returns atan2(y,x) * (127/pi).
// Hastings deg-9 odd minimax on [0,1], max err ~1e-5 rad (4e-4 int8 code
// flips => ~1e-7 relative error on the final mean).
__device__ __forceinline__ float fast_atan2q(float y, float x) {
    const float ax = __builtin_fabsf(x);
    const float ay = __builtin_fabsf(y);
    const float mx = fmaxf(ax, ay);
    const float mn = fminf(ax, ay);
    const float t  = mn * __builtin_amdgcn_rcpf(mx);   // in [0,1]
    const float t2 = t * t;
    // coefficients pre-scaled by 127/pi
    float p = fmaf(t2, fmaf(t2, fmaf(t2, fmaf(t2,
                  0.84219761f, -3.44137383f), 7.28200966f), -13.35163894f),
                  40.42416382f);
    p *= t;
    p = (ay > ax) ? (63.5f - p) : p;     // 127/pi * (pi/2 - atan)
    p = (x < 0.0f) ? (127.0f - p) : p;   // 127/pi * (pi - atan)
    return copysignf(p, y);
}

// ---- kernel 1: transpose + atan2 + int8 quantize -> th[NB][BATCH],
//      plus fully-parallel row_start precompute (hidden under mem-bound
//      theta work; rows = 640 KB, L2-resident). NO fences, NO counters.
//      This exact structure measured 41.4 us / total 147.8 us (R5). -------
__global__ __launch_bounds__(256) void theta_k(
        const float4* __restrict__ c4, const float4* __restrict__ s4,
        signed char* __restrict__ th, int* __restrict__ row_start,
        const int* __restrict__ rows, int E) {
    __shared__ signed char t[64][68];       // [b_local][nb_local], 68 = 4*17
    const int u = threadIdx.x;

    if (blockIdx.y == 0) {
        const int g = blockIdx.x * 256 + u;
        if (g <= NCYC) {
            int lo = 0, hi = E;
            while (lo < hi) { const int m = (lo + hi) >> 1; if (rows[m] < g) lo = m + 1; else hi = m; }
            row_start[g] = lo;
        }
    }

    const int col4 = u & 15;                // nb4 within tile
    const int brow = u >> 4;                // 0..15
    const int x4   = blockIdx.x * 16 + col4;
    const int bb   = blockIdx.y * 64;

    if (x4 < NB4) {
        #pragma unroll
        for (int j = 0; j < 4; ++j) {
            const int bl = brow + 16 * j;   // b_local 0..63
            const float4 vc = c4[(size_t)(bb + bl) * NB4 + x4];
            const float4 vs = s4[(size_t)(bb + bl) * NB4 + x4];
            char4 q;
            q.x = (signed char)__float2int_rn(fast_atan2q(vs.x, vc.x));
            q.y = (signed char)__float2int_rn(fast_atan2q(vs.y, vc.y));
            q.z = (signed char)__float2int_rn(fast_atan2q(vs.z, vc.z));
            q.w = (signed char)__float2int_rn(fast_atan2q(vs.w, vc.w));
            *reinterpret_cast<char4*>(&t[bl][4 * col4]) = q;
        }
    }
    __syncthreads();
    // store phase: 16 lanes cover 64 consecutive b (64B) per nb
    const int g   = u & 15;                 // char4 group along b
    const int nb0 = u >> 4;                 // 0..15
    #pragma unroll
    for (int j = 0; j < 4; ++j) {
        const int nbl = nb0 + 16 * j;       // 0..63
        const int nb  = blockIdx.x * 64 + nbl;
        if (nb < NB) {
            char4 v;
            v.x = t[4 * g + 0][nbl];
            v.y = t[4 * g + 1][nbl];
            v.z = t[4 * g + 2][nbl];
            v.w = t[4 * g + 3][nbl];
            *reinterpret_cast<char4*>(&th[(size_t)nb * BATCH + bb + 4 * g]) = v;
        }
    }
}

// ---- kernel 2: wave per row (4/block), precomputed bounds, NO fences,
//      one partial per block ----------------------------------------------
__global__ __launch_bounds__(256) void kvl3_k(
        const signed char* __restrict__ th,
        const float* __restrict__ signs, const int* __restrict__ inds,
        const int* __restrict__ row_start,
        float* __restrict__ partials) {
    __shared__ float wsum[4];
    const int tid  = threadIdx.x;
    const int wave = tid >> 6;
    const int lane = tid & 63;
    const int r    = blockIdx.x * 4 + wave;           // < NCYC (5000*4)
    const int start = row_start[r];
    const int end   = row_start[r + 1];

    float a0 = 0.f, a1 = 0.f, a2 = 0.f, a3 = 0.f;
    int e = start;
    for (; e + 2 <= end; e += 2) {
        const int   i0 = inds[e],  i1 = inds[e + 1];
        const float g0 = signs[e] * DQSCALE, g1 = signs[e + 1] * DQSCALE;
        const unsigned int u0 = *reinterpret_cast<const unsigned int*>(&th[(size_t)i0 * BATCH + lane * 4]);
        const unsigned int u1 = *reinterpret_cast<const unsigned int*>(&th[(size_t)i1 * BATCH + lane * 4]);
        a0 += g0 * (float)(signed char)(u0      ) + g1 * (float)(signed char)(u1      );
        a1 += g0 * (float)(signed char)(u0 >>  8) + g1 * (float)(signed char)(u1 >>  8);
        a2 += g0 * (float)(signed char)(u0 >> 16) + g1 * (float)(signed char)(u1 >> 16);
        a3 += g0 * (float)(signed char)(u0 >> 24) + g1 * (float)(signed char)(u1 >> 24);
    }
    if (e < end) {
        const float g0 = signs[e] * DQSCALE;
        const unsigned int u0 = *reinterpret_cast<const unsigned int*>(&th[(size_t)inds[e] * BATCH + lane * 4]);
        a0 += g0 * (float)(signed char)(u0      );
        a1 += g0 * (float)(signed char)(u0 >>  8);
        a2 += g0 * (float)(signed char)(u0 >> 16);
        a3 += g0 * (float)(signed char)(u0 >> 24);
    }
    float v = fabsf(a0) + fabsf(a1) + fabsf(a2) + fabsf(a3);
    #pragma unroll
    for (int off = 32; off > 0; off >>= 1)
        v += __shfl_down(v, off, 64);
    if (lane == 0) wsum[wave] = v;
    __syncthreads();
    if (tid == 0)
        partials[blockIdx.x] = wsum[0] + wsum[1] + wsum[2] + wsum[3];
}

// ---- kernel 3: single block reduces 5000 block partials -> out[0] ---------
__global__ __launch_bounds__(1024) void reduce_k(
        const float* __restrict__ partials, float* __restrict__ out) {
    const int tid = threadIdx.x;
    float v = 0.f;
    for (int i = tid; i < NCYC / 4; i += 1024) v += partials[i];
    #pragma unroll
    for (int off = 32; off > 0; off >>= 1)
        v += __shfl_down(v, off, 64);
    __shared__ float wsum[16];
    if ((tid & 63) == 0) wsum[tid >> 6] = v;
    __syncthreads();
    if (tid == 0) {
        float t = 0.f;
        #pragma unroll
        for (int w = 0; w < 16; ++w) t += wsum[w];
        out[0] = t * OUTSCALE;
    }
}

// ---- fallback (no workspace): direct strided gather -----------------------
__global__ void zero_out_k(float* out) { if (threadIdx.x == 0) out[0] = 0.0f; }

__global__ __launch_bounds__(256) void kvl_fallback_k(
        const float* __restrict__ c, const float* __restrict__ s,
        const float* __restrict__ signs, const int* __restrict__ inds,
        const int* __restrict__ rows, int E, float* __restrict__ out) {
    const int r = blockIdx.x;
    int lo = 0, hi = E;
    while (lo < hi) { const int m = (lo + hi) >> 1; if (rows[m] < r) lo = m + 1; else hi = m; }
    const int start = lo;
    hi = E;
    while (lo < hi) { const int m = (lo + hi) >> 1; if (rows[m] <= r) lo = m + 1; else hi = m; }
    const int end = lo;
    const int tid = threadIdx.x;
    float acc = 0.f;
    for (int e = start; e < end; ++e) {
        const int idx = inds[e];
        const float sg = signs[e];
        acc += atan2f(sg * s[(size_t)tid * NB + idx], c[(size_t)tid * NB + idx]);
    }
    float v = fabsf(acc);
    #pragma unroll
    for (int off = 32; off > 0; off >>= 1)
        v += __shfl_down(v, off, 64);
    __shared__ float wsum[4];
    if ((tid & 63) == 0) wsum[tid >> 6] = v;
    __syncthreads();
    if (tid == 0)
        atomicAdd(out, (wsum[0] + wsum[1] + wsum[2] + wsum[3]) *
                       (1.0f / ((float)NCYC * (float)BATCH)));
}

extern "C" void kernel_launch(void* const* d_in, const int* in_sizes, int n_in,
                              void* d_out, int out_size, void* d_ws, size_t ws_size,
                              hipStream_t stream) {
    const float* c       = (const float*)d_in[0];
    const float* s       = (const float*)d_in[1];
    const float* cysigns = (const float*)d_in[2];
    const int*   cyinds  = (const int*)d_in[3];
    const int*   cyrows  = (const int*)d_in[4];
    const int    E       = in_sizes[2];   // 160000
    float* out = (float*)d_out;

    const size_t th_bytes = (size_t)NB * BATCH;            // 12.8 MB int8
    const size_t rs_bytes = (size_t)(NCYC + 1) * sizeof(int);
    const size_t pa_bytes = (size_t)(NCYC / 4) * sizeof(float);
    const size_t need = th_bytes + rs_bytes + pa_bytes;
    if (ws_size >= need) {
        signed char* th   = (signed char*)d_ws;
        int* row_start    = (int*)(th + th_bytes);
        float* partials   = (float*)((char*)row_start + rs_bytes);

        dim3 tg((NB4 + 15) / 16, BATCH / 64);              // (782, 4)
        theta_k<<<tg, 256, 0, stream>>>((const float4*)c, (const float4*)s,
                                        th, row_start, cyrows, E);
        kvl3_k<<<NCYC / 4, 256, 0, stream>>>(th, cysigns, cyinds, row_start,
                                             partials);
        reduce_k<<<1, 1024, 0, stream>>>(partials, out);
    } else {
        zero_out_k<<<1, 64, 0, stream>>>(out);
        kvl_fallback_k<<<NCYC, 256, 0, stream>>>(c, s, cysigns, cyinds, cyrows, E, out);
    }
}